// Round 3
// baseline (343.859 us; speedup 1.0000x reference)
//
#include <hip/hip_runtime.h>

// Problem constants (fixed by the reference file).
#define SAMPLES 16
#define NEVENTS (1 << 20)          // 1048576
#define FRAMES  16
#define FSZ     128
#define WIN     (NEVENTS / FRAMES) // 65536 events per frame
#define BINS    (FSZ * FSZ)        // 16384 (y*128 + x)
#define TPB     1024
#define EPT     16                 // events per thread per pipeline step
#define STEPS   (WIN / (EPT * TPB)) // 4 steps, fully unrolled ping-pong

// clang ext-vector types (true vector types: accepted by
// __builtin_nontemporal_{load,store}, support .x/.y/.z/.w).
typedef float v4f __attribute__((ext_vector_type(4)));
typedef int   v4i __attribute__((ext_vector_type(4)));

// Structure (measured best): ONE kernel, one block per (frame, sample).
// Block owns out[f, s, :, :, :] (2*BINS floats = 128 KB LDS) exclusively ->
// pure LDS privatization, no global atomics, poisoned d_out fully
// overwritten by its owner block.
//
// R2 post-mortem: load-side pipelining changed nothing (dur delta == fill
// noise). Pipe arithmetic says loads <=10us, HBM floor ~16-20us, VALU ~2us;
// the ~95us kernel time can only live in the DS-atomic path: 1024
// wave-scatter ds_add_f32 per CU at ~93 cy each (per-bank RMW turnaround x
// max-bank-load ~6 for random x & 31). This revision separates each step
// into PREP (all 16 byte-offsets + |v| into registers; register-only deps)
// and BURST (16 back-to-back ds_add_f32, no waits inside) so independent
// atomics from consecutive instructions can pipeline in the DS unit and the
// per-bank turnaround amortizes across the burst.

// Compute plane|y|x element offsets and |v| for 4 events. off/av are written
// with literal indices only (SROA keeps them in registers).
__device__ __forceinline__ void prep4(v4f v, v4i xv, v4i yv, int* off, float* av) {
    // plane bit: 1 if v>=0 (pos plane, +BINS=+1<<14), 0 if v<0 (neg plane).
    // v==+-0 adds 0.0f -> no-op either way. y<128, x<128 -> OR is exact.
    const unsigned ux = __float_as_uint(v.x), uy = __float_as_uint(v.y),
                   uz = __float_as_uint(v.z), uw = __float_as_uint(v.w);
    off[0] = (int)((((~ux) >> 31) << 14) | ((unsigned)yv.x << 7) | (unsigned)xv.x);
    off[1] = (int)((((~uy) >> 31) << 14) | ((unsigned)yv.y << 7) | (unsigned)xv.y);
    off[2] = (int)((((~uz) >> 31) << 14) | ((unsigned)yv.z << 7) | (unsigned)xv.z);
    off[3] = (int)((((~uw) >> 31) << 14) | ((unsigned)yv.w << 7) | (unsigned)xv.w);
    av[0] = __builtin_fabsf(v.x);
    av[1] = __builtin_fabsf(v.y);
    av[2] = __builtin_fabsf(v.z);
    av[3] = __builtin_fabsf(v.w);
}

// One step = 16 events/thread = 4 coalesced v4 chunks (chunk c, thread tid ->
// vector index step*4*TPB + c*TPB + tid). ev is stream-once -> nontemporal.
#define LOADSTEP(B, step)                                                        \
    v##B##0 = __builtin_nontemporal_load(&ev4[(step) * 4 * TPB + 0 * TPB + tid]);\
    v##B##1 = __builtin_nontemporal_load(&ev4[(step) * 4 * TPB + 1 * TPB + tid]);\
    v##B##2 = __builtin_nontemporal_load(&ev4[(step) * 4 * TPB + 2 * TPB + tid]);\
    v##B##3 = __builtin_nontemporal_load(&ev4[(step) * 4 * TPB + 3 * TPB + tid]);\
    x##B##0 = x4[(step) * 4 * TPB + 0 * TPB + tid];                              \
    x##B##1 = x4[(step) * 4 * TPB + 1 * TPB + tid];                              \
    x##B##2 = x4[(step) * 4 * TPB + 2 * TPB + tid];                              \
    x##B##3 = x4[(step) * 4 * TPB + 3 * TPB + tid];                              \
    y##B##0 = y4[(step) * 4 * TPB + 0 * TPB + tid];                              \
    y##B##1 = y4[(step) * 4 * TPB + 1 * TPB + tid];                              \
    y##B##2 = y4[(step) * 4 * TPB + 2 * TPB + tid];                              \
    y##B##3 = y4[(step) * 4 * TPB + 3 * TPB + tid];

// PREP: resolve all 16 addresses/values into registers (no memory deps left).
#define PREP(B)                                                                  \
    prep4(v##B##0, x##B##0, y##B##0, &off[0],  &av[0]);                          \
    prep4(v##B##1, x##B##1, y##B##1, &off[4],  &av[4]);                          \
    prep4(v##B##2, x##B##2, y##B##2, &off[8],  &av[8]);                          \
    prep4(v##B##3, x##B##3, y##B##3, &off[12], &av[12]);

// BURST: 16 back-to-back ds_add_f32, register-only operands -> no s_waitcnt
// can land inside; DS unit pipelines across the independent atomics.
#define BURST()                                                                  \
    _Pragma("unroll")                                                            \
    for (int k = 0; k < 16; ++k) atomicAdd(&lds[off[k]], av[k]);

__global__ __launch_bounds__(TPB) void frame_accum_kernel(
    const float* __restrict__ ev,   // [S, N] event_values
    const int*   __restrict__ idx,  // [S, 3, N]; only [0,1,:] (x), [0,2,:] (y) used
    float*       __restrict__ out)  // [F, S, 2, Y, X]
{
    extern __shared__ float lds[];  // [2][BINS]: plane 0 = neg, plane 1 = pos
    const int tid = threadIdx.x;
    const int s = blockIdx.x & (SAMPLES - 1);
    const int f = blockIdx.x >> 4;

    // Zero the private accumulator.
    v4f* lds4 = (v4f*)lds;
    const v4f zero4 = (v4f)(0.f);
#pragma unroll
    for (int i = 0; i < (2 * BINS / 4) / TPB; ++i)   // 8 iters
        lds4[i * TPB + tid] = zero4;
    __syncthreads();

    // This block's event slice: events [f*WIN, (f+1)*WIN), sample s.
    const v4f* ev4 = (const v4f*)(ev  + (size_t)s * NEVENTS + (size_t)f * WIN);
    const v4i* x4  = (const v4i*)(idx + (size_t)NEVENTS      + (size_t)f * WIN); // indices[0,1,:]
    const v4i* y4  = (const v4i*)(idx + (size_t)2 * NEVENTS  + (size_t)f * WIN); // indices[0,2,:]

    v4f vA0, vA1, vA2, vA3, vB0, vB1, vB2, vB3;
    v4i xA0, xA1, xA2, xA3, xB0, xB1, xB2, xB3;
    v4i yA0, yA1, yA2, yA3, yB0, yB1, yB2, yB3;
    int   off[16];
    float av[16];

    LOADSTEP(A, 0)
#pragma unroll
    for (int st = 0; st < STEPS; st += 2) {
        LOADSTEP(B, st + 1)                  // next step's 12 loads in flight
        PREP(A)                              // resolve A into registers
        BURST()                              // 16 back-to-back ds_add_f32
        if (st + 2 < STEPS) { LOADSTEP(A, st + 2) }
        PREP(B)
        BURST()
    }
    __syncthreads();

    // Coalesced write of the exclusive slice: out[f, s, p, y, x]; LDS layout
    // (neg plane first) matches the output plane order exactly. Nontemporal:
    // out is write-once, never re-read.
    v4f* op4 = (v4f*)(out + ((size_t)(f * SAMPLES + s)) * 2 * BINS);
#pragma unroll
    for (int i = 0; i < (2 * BINS / 4) / TPB; ++i)   // 8 iters
        __builtin_nontemporal_store(lds4[i * TPB + tid], &op4[i * TPB + tid]);
}

extern "C" void kernel_launch(void* const* d_in, const int* in_sizes, int n_in,
                              void* d_out, int out_size, void* d_ws, size_t ws_size,
                              hipStream_t stream) {
    const float* ev  = (const float*)d_in[0];
    const int*   idx = (const int*)d_in[1];
    // d_in[2] = use_soft, fixed 0 (hard path) -> ignored.
    float* out = (float*)d_out;

    // 128 KB dynamic LDS per block; gfx950 GROUP segment is 160 KB/CU.
    (void)hipFuncSetAttribute((const void*)frame_accum_kernel,
                              hipFuncAttributeMaxDynamicSharedMemorySize,
                              2 * BINS * (int)sizeof(float));

    frame_accum_kernel<<<FRAMES * SAMPLES, TPB, 2 * BINS * sizeof(float), stream>>>(
        ev, idx, out);
}